// Round 15
// baseline (300.862 us; speedup 1.0000x reference)
//
#include <hip/hip_runtime.h>

// ---- problem constants ----
#define D_DIM 1024
#define B_DIM 16
#define T_DIM 2048
#define M_TOT (B_DIM * T_DIM)   // 32768 rows
#define K_DIM 1024
#define LN_EPS 1e-5f
#define CHUNK 16
#define NCH (T_DIM / CHUNK)     // 128 chunks

typedef _Float16 half8 __attribute__((ext_vector_type(8)));
typedef _Float16 half4v __attribute__((ext_vector_type(4)));
typedef float f32x4 __attribute__((ext_vector_type(4)));

// ------- merged prep: x cvt | gate cvt | W_state cvt | W_vx transpose -------
__global__ __launch_bounds__(256) void prep_all(const float* __restrict__ x,
                                                const float* __restrict__ W_in,
                                                const float* __restrict__ W_state,
                                                _Float16* __restrict__ xh,
                                                _Float16* __restrict__ Wall,
                                                _Float16* __restrict__ wvxT,
                                                _Float16* __restrict__ wst) {
    __shared__ _Float16 t[32][33];
    int b = blockIdx.x, tid = threadIdx.x;
    if (b < 2048) {                      // x -> fp16, grid-stride (4M half8 units)
        int i = b * 256 + tid;
        for (; i < M_TOT * K_DIM / 8; i += 2048 * 256) {
            const float4* p = (const float4*)x + 2 * (size_t)i;
            float4 a = p[0], c = p[1];
            half8 h;
            h[0] = (_Float16)a.x; h[1] = (_Float16)a.y; h[2] = (_Float16)a.z; h[3] = (_Float16)a.w;
            h[4] = (_Float16)c.x; h[5] = (_Float16)c.y; h[6] = (_Float16)c.z; h[7] = (_Float16)c.w;
            ((half8*)xh)[i] = h;
        }
    } else if (b < 2560) {               // W_g -> Wall rows 0..1023
        int i = (b - 2048) * 256 + tid;
        const float4* p = (const float4*)W_in + 2 * (size_t)i;
        float4 a = p[0], c = p[1];
        half8 h;
        h[0] = (_Float16)a.x; h[1] = (_Float16)a.y; h[2] = (_Float16)a.z; h[3] = (_Float16)a.w;
        h[4] = (_Float16)c.x; h[5] = (_Float16)c.y; h[6] = (_Float16)c.z; h[7] = (_Float16)c.w;
        ((half8*)Wall)[i] = h;
    } else if (b < 3072) {               // W_state -> wst
        int i = (b - 2560) * 256 + tid;
        const float4* p = (const float4*)W_state + 2 * (size_t)i;
        float4 a = p[0], c = p[1];
        half8 h;
        h[0] = (_Float16)a.x; h[1] = (_Float16)a.y; h[2] = (_Float16)a.z; h[3] = (_Float16)a.w;
        h[4] = (_Float16)c.x; h[5] = (_Float16)c.y; h[6] = (_Float16)c.z; h[7] = (_Float16)c.w;
        ((half8*)wst)[i] = h;
    } else {                             // W_vx^T -> wvxT (32x32 tiles)
        int tile = b - 3072;             // 0..1023
        int bx = (tile & 31) * 32, by = (tile >> 5) * 32;
        int tx = tid & 31, ty = tid >> 5; // (32,8)
        const float* src = W_in + (size_t)D_DIM * K_DIM;
#pragma unroll
        for (int j = 0; j < 4; ++j)
            t[ty + 8 * j][tx] = (_Float16)src[(size_t)(by + ty + 8 * j) * 1024 + bx + tx];
        __syncthreads();
#pragma unroll
        for (int j = 0; j < 4; ++j)
            wvxT[(size_t)(bx + ty + 8 * j) * 1024 + by + tx] = t[tx][ty + 8 * j];
    }
}

// ---------------- async global->LDS helper ----------------
__device__ __forceinline__ void gl_lds16(const _Float16* g, _Float16* l) {
    __builtin_amdgcn_global_load_lds(
        (const __attribute__((address_space(1))) unsigned int*)g,
        (__attribute__((address_space(3))) unsigned int*)l,
        16, 0, 0);
}

// ====== 128x256 fp16 MFMA GEMM (r13-proven skeleton) + paired gate/cand B ======
// Each block computes BOTH u and cand for the same 128 cols x 128 rows, so the
// epilogue can compose the per-16-row affine scan segments in-register and
// write Ac/Bc directly (scan_pass1 eliminated).
// Sync skeleton unchanged from r13: vmcnt(6) -> barrier -> ds_reads -> stage
// S_{t+2} -> MFMA ; 3-buffer LDS ; 0 bank conflicts (both-sides XOR swizzle).

// Stage 128x32 A-tile (8 KiB, 512 chunks) = 2 gl_lds / thread.
__device__ __forceinline__ void stageA32(const _Float16* __restrict__ G,
                                         int row0, int kt,
                                         _Float16* lds0, int wid, int lane) {
#pragma unroll
    for (int call = 0; call < 2; ++call) {
        int c0 = call * 256 + wid * 64;
        int c  = c0 + lane;                 // chunk 0..511
        int rl = c >> 2;                    // row 0..127
        int cc = c & 3;
        int src = cc ^ ((rl >> 1) & 3);
        gl_lds16(G + (size_t)(row0 + rl) * 1024 + kt + src * 8,
                 lds0 + (size_t)c0 * 8);
    }
}

// Stage paired B-tile: 256 LDS rows = W rows [nt*128,+128) then [1024+nt*128,+128).
__device__ __forceinline__ void stageB32(const _Float16* __restrict__ G,
                                         int nt, int kt,
                                         _Float16* lds0, int wid, int lane) {
#pragma unroll
    for (int call = 0; call < 4; ++call) {
        int c0 = call * 256 + wid * 64;
        int c  = c0 + lane;                 // chunk 0..1023
        int rl = c >> 2;                    // lds row 0..255
        int cc = c & 3;
        int src = cc ^ ((rl >> 1) & 3);
        int row = nt * 128 + (rl & 127) + ((rl >> 7) << 10);   // gate | comb
        gl_lds16(G + (size_t)row * 1024 + kt + src * 8,
                 lds0 + (size_t)c0 * 8);
    }
}

// Fragment read with matching XOR (conflict-free, measured r7/r13).
__device__ __forceinline__ half8 frag32(const _Float16* base, int row, int kq) {
    int cc = kq ^ ((row >> 1) & 3);
    return *(const half8*)(base + (size_t)row * 32 + cc * 8);
}

template <int TB>
__device__ __forceinline__ void gstep(const _Float16* __restrict__ A,
                                      const _Float16* __restrict__ W,
                                      int m0, int nt, int t, int nkt,
                                      int wid, int lane, int wc, int r, int kq,
                                      _Float16 (&As)[3][128][32],
                                      _Float16 (&Bs)[3][256][32],
                                      f32x4 (&acc)[8][4]) {
    constexpr int NB = (TB + 2) % 3;
    half8 rb[4], ra0[4], ra1[4];

    // ---- tile top: own vmcnt lands S_t ; barrier publishes all waves' S_t ----
    if (t + 1 < nkt) asm volatile("s_waitcnt vmcnt(6)" ::: "memory");
    else             asm volatile("s_waitcnt vmcnt(0)" ::: "memory");
    __builtin_amdgcn_s_barrier();
    __builtin_amdgcn_sched_barrier(0);       // pin reads below barrier (rule #18)

    // ---- ph0: ds rb+ra0 ; stage S_{t+2} ; MFMA 0..3 ----
    // rb[ni]: ni<2 -> gate cols (lds rows wc*32+ni*16+r), ni>=2 -> comb (+128)
#pragma unroll
    for (int ni = 0; ni < 4; ni++)
        rb[ni] = frag32(&Bs[TB][0][0], (ni >> 1) * 128 + wc * 32 + (ni & 1) * 16 + r, kq);
#pragma unroll
    for (int mi = 0; mi < 4; mi++) ra0[mi] = frag32(&As[TB][0][0], mi * 16 + r, kq);
    if (t + 2 < nkt) {
        int kt2 = (t + 2) << 5;
        stageA32(A, m0, kt2, &As[NB][0][0], wid, lane);
        stageB32(W, nt, kt2, &Bs[NB][0][0], wid, lane);
    }
    __builtin_amdgcn_s_setprio(1);
#pragma unroll
    for (int mi = 0; mi < 4; mi++)
#pragma unroll
        for (int ni = 0; ni < 4; ni++)
            acc[mi][ni] = __builtin_amdgcn_mfma_f32_16x16x32_f16(ra0[mi], rb[ni], acc[mi][ni], 0, 0, 0);
    __builtin_amdgcn_s_setprio(0);

    // ---- ph1: ds ra1 ; MFMA 4..7 ; end barrier ----
#pragma unroll
    for (int mi = 0; mi < 4; mi++) ra1[mi] = frag32(&As[TB][0][0], 64 + mi * 16 + r, kq);
    __builtin_amdgcn_s_setprio(1);
#pragma unroll
    for (int mi = 0; mi < 4; mi++)
#pragma unroll
        for (int ni = 0; ni < 4; ni++)
            acc[4 + mi][ni] = __builtin_amdgcn_mfma_f32_16x16x32_f16(ra1[mi], rb[ni], acc[4 + mi][ni], 0, 0, 0);
    __builtin_amdgcn_s_setprio(0);
    __builtin_amdgcn_s_barrier();
}

__global__ __launch_bounds__(256, 2) void gemm256(const _Float16* __restrict__ A,
                                                  const _Float16* __restrict__ W,
                                                  _Float16* __restrict__ out_u,
                                                  _Float16* __restrict__ out_c,
                                                  float* __restrict__ Ac,
                                                  float* __restrict__ Bc) {
    __shared__ _Float16 As[3][128][32];   // 24 KiB
    __shared__ _Float16 Bs[3][256][32];   // 48 KiB  (72 KiB -> 2 blocks/CU)

    int bid = blockIdx.x;                 // 2048 blocks
    int xcd = bid & 7, lin = bid >> 3;    // 256 blocks/XCD
    int mt = xcd * 32 + (lin >> 3);       // 32 mt x 8 nt per XCD (x panel reused 8x)
    int nt = lin & 7;                     // 128-col pair (gate + comb)
    int m0 = mt * 128;

    int tid = threadIdx.x, wid = tid >> 6, lane = tid & 63;
    int wc = wid;                          // wave owns 32 paired cols
    int r = lane & 15, kq = lane >> 4;

    f32x4 acc[8][4];
#pragma unroll
    for (int i = 0; i < 8; i++)
#pragma unroll
        for (int j = 0; j < 4; j++) acc[i][j] = (f32x4)0.f;

    const int nkt = K_DIM >> 5;            // 32 K-tiles

    // ---- prologue: stage tiles 0,1 ; loop-top vmcnt handles the wait ----
    stageA32(A, m0, 0,  &As[0][0][0], wid, lane);
    stageB32(W, nt, 0,  &Bs[0][0][0], wid, lane);
    stageA32(A, m0, 32, &As[1][0][0], wid, lane);
    stageB32(W, nt, 32, &Bs[1][0][0], wid, lane);

    for (int t0 = 0; t0 < nkt; t0 += 3) {
        gstep<0>(A, W, m0, nt, t0, nkt, wid, lane, wc, r, kq, As, Bs, acc);
        if (t0 + 1 < nkt)
            gstep<1>(A, W, m0, nt, t0 + 1, nkt, wid, lane, wc, r, kq, As, Bs, acc);
        if (t0 + 2 < nkt)
            gstep<2>(A, W, m0, nt, t0 + 2, nkt, wid, lane, wc, r, kq, As, Bs, acc);
    }

    // ---- epilogue: write u/cand fp16 AND per-16-row affine segments ----
    // C/D layout: col = lane&15 (=r), row = kq*4 + q (+ mi*16). t_local = kq*4+q.
    int rr = kq * 4;
#pragma unroll
    for (int mi = 0; mi < 8; mi++) {
        int mbase = m0 + mi * 16 + rr;
        float Aab[2] = {1.f, 1.f}, Bab[2] = {0.f, 0.f};
#pragma unroll
        for (int ni = 0; ni < 2; ni++) {
            int d = nt * 128 + wc * 32 + ni * 16 + r;
#pragma unroll
            for (int q = 0; q < 4; q++) {   // t ascending within lane's 4-run
                float u = 1.f / (1.f + __expf(-acc[mi][ni][q]));
                float c = acc[mi][ni + 2][q];
                size_t m = (size_t)(mbase + q);
                out_u[m * D_DIM + d] = (_Float16)u;
                out_c[m * D_DIM + d] = (_Float16)c;
                Bab[ni] = fmaf(u, Bab[ni], (1.f - u) * c);
                Aab[ni] *= u;
            }
        }
        // ordered butterfly compose across the 4 kq lanes (t-runs kq*4..+4)
#pragma unroll
        for (int ni = 0; ni < 2; ni++) {
            float Aa = Aab[ni], Bb = Bab[ni];
            float oA = __shfl_xor(Aa, 16), oB = __shfl_xor(Bb, 16);
            if (kq & 1) { Bb = fmaf(Aa, oB, Bb); Aa *= oA; }   // mine later
            else        { Bb = fmaf(oA, Bb, oB); Aa *= oA; }   // other later
            oA = __shfl_xor(Aa, 32); oB = __shfl_xor(Bb, 32);
            if (kq & 2) { Bb = fmaf(Aa, oB, Bb); Aa *= oA; }
            else        { Bb = fmaf(oA, Bb, oB); Aa *= oA; }
            if (kq == 0) {
                int d = nt * 128 + wc * 32 + ni * 16 + r;
                int bc = mt * 8 + mi;        // global 16-chunk id = b*NCH + ch
                Ac[(size_t)bc * 1024 + d] = Aa;
                Bc[(size_t)bc * 1024 + d] = Bb;
            }
        }
    }
}

// ========== split-K W_comb GEMM (128x128 tile, r2-validated structure) ==========
__global__ __launch_bounds__(256) void wcomb_splitk(const _Float16* __restrict__ A,
                                                    const _Float16* __restrict__ Bm,
                                                    float* __restrict__ part) {
    __shared__ _Float16 As[128 * 32];
    __shared__ _Float16 Bs[128 * 32];
    int bid = blockIdx.x;                 // mt + 8*nt + 64*slice
    int mt = bid & 7, nt = (bid >> 3) & 7, sl = bid >> 6;
    int m0 = mt * 128, n0 = nt * 128, kbeg = sl * 256;
    int tid = threadIdx.x, wid = tid >> 6, lane = tid & 63;
    int wr = wid >> 1, wc = wid & 1;

    f32x4 acc[4][4];
#pragma unroll
    for (int i = 0; i < 4; i++)
#pragma unroll
        for (int j = 0; j < 4; j++) acc[i][j] = (f32x4)0.f;

    int r = lane & 15, kq = lane >> 4;

    for (int kt = kbeg; kt < kbeg + 256; kt += 32) {
        __syncthreads();
#pragma unroll
        for (int j = 0; j < 2; ++j) {
            int f = j * 256 + tid;
            int row = f >> 2, kc = f & 3;
            gl_lds16(A + (size_t)(m0 + row) * 1024 + kt + kc * 8, As + (size_t)(j * 256 + wid * 64) * 8);
            gl_lds16(Bm + (size_t)(n0 + row) * 1024 + kt + kc * 8, Bs + (size_t)(j * 256 + wid * 64) * 8);
        }
        __syncthreads();
        half8 af[4], bf[4];
#pragma unroll
        for (int mi = 0; mi < 4; mi++) af[mi] = *(const half8*)&As[(wr * 64 + mi * 16 + r) * 32 + kq * 8];
#pragma unroll
        for (int ni = 0; ni < 4; ni++) bf[ni] = *(const half8*)&Bs[(wc * 64 + ni * 16 + r) * 32 + kq * 8];
#pragma unroll
        for (int mi = 0; mi < 4; mi++)
#pragma unroll
            for (int ni = 0; ni < 4; ni++)
                acc[mi][ni] = __builtin_amdgcn_mfma_f32_16x16x32_f16(af[mi], bf[ni], acc[mi][ni], 0, 0, 0);
    }

    int rr = kq * 4;
    float* pbp = part + (size_t)sl * 1048576;
#pragma unroll
    for (int mi = 0; mi < 4; mi++) {
        int mbase = m0 + wr * 64 + mi * 16 + rr;
#pragma unroll
        for (int ni = 0; ni < 4; ni++) {
            int n = n0 + wc * 64 + ni * 16 + r;
#pragma unroll
            for (int q = 0; q < 4; q++)
                pbp[(size_t)(mbase + q) * 1024 + n] = acc[mi][ni][q];
        }
    }
}

// combine 4 split-K slices -> Wall rows 1024..2047 (row-major fp16)
__global__ __launch_bounds__(256) void wcomb_combine(const float* __restrict__ part,
                                                     _Float16* __restrict__ out) {
    int i = blockIdx.x * 256 + threadIdx.x;   // 0..262143 (float4 units)
    float4 s0 = ((const float4*)part)[i];
    float4 s1 = ((const float4*)(part + 1048576))[i];
    float4 s2 = ((const float4*)(part + 2097152))[i];
    float4 s3 = ((const float4*)(part + 3145728))[i];
    half4v o;
    o[0] = (_Float16)(s0.x + s1.x + s2.x + s3.x);
    o[1] = (_Float16)(s0.y + s1.y + s2.y + s3.y);
    o[2] = (_Float16)(s0.z + s1.z + s2.z + s3.z);
    o[3] = (_Float16)(s0.w + s1.w + s2.w + s3.w);
    ((half4v*)out)[i] = o;
}

// pass 2: sequential over 128 chunks; AcH0 doubles as h0 output (read-before-write)
__global__ __launch_bounds__(256) void scan_pass2(float* __restrict__ AcH0,
                                                  const float* __restrict__ Bc) {
    int idx = blockIdx.x * 256 + threadIdx.x;   // b*D + d, 16384 total
    int b = idx >> 10, d = idx & (D_DIM - 1);
    float h = 0.f;
#pragma unroll 8
    for (int ch = 0; ch < NCH; ++ch) {
        size_t k = ((size_t)(b * NCH + ch) << 10) + d;
        float a = AcH0[k];
        float bv = Bc[k];
        AcH0[k] = h;
        h = fmaf(a, h, bv);
    }
}

// ---------------- fused scan pass 3 + LayerNorm (1 wave, 16 dims/lane) ----------------
__global__ __launch_bounds__(64) void scan_ln(const _Float16* __restrict__ u,
                                              const _Float16* __restrict__ cd,
                                              const float* __restrict__ h0,
                                              const float* __restrict__ gamma,
                                              const float* __restrict__ beta,
                                              float* __restrict__ outp) {
    int bc = blockIdx.x;                // b*NCH + ch
    int b = bc >> 7, ch = bc & (NCH - 1);
    int lane = threadIdx.x;             // 0..63
    int d0 = lane * 16;
    size_t base = ((size_t)b * T_DIM + (size_t)ch * CHUNK) * D_DIM + d0;

    float g[16], be[16], h[16];
#pragma unroll
    for (int j = 0; j < 16; j += 4) {
        *(float4*)&g[j]  = *(const float4*)&gamma[d0 + j];
        *(float4*)&be[j] = *(const float4*)&beta[d0 + j];
    }
    size_t o = (size_t)bc * D_DIM + d0;
#pragma unroll
    for (int j = 0; j < 16; j += 4) *(float4*)&h[j] = *(const float4*)&h0[o + j];

    for (int t = 0; t < CHUNK; ++t) {
        size_t row = base + (size_t)t * D_DIM;
        half8 ua = *(const half8*)&u[row];
        half8 ub = *(const half8*)&u[row + 8];
        half8 ca = *(const half8*)&cd[row];
        half8 cb = *(const half8*)&cd[row + 8];
        float s = 0.f, q = 0.f;
#pragma unroll
        for (int j = 0; j < 8; ++j) {
            float ut = (float)ua[j], ct = (float)ca[j];
            h[j] = fmaf(ut, h[j] - ct, ct);
            s += h[j]; q += h[j] * h[j];
        }
#pragma unroll
        for (int j = 0; j < 8; ++j) {
            float ut = (float)ub[j], ct = (float)cb[j];
            h[8 + j] = fmaf(ut, h[8 + j] - ct, ct);
            s += h[8 + j]; q += h[8 + j] * h[8 + j];
        }
#pragma unroll
        for (int off = 32; off > 0; off >>= 1) {
            s += __shfl_xor(s, off);
            q += __shfl_xor(q, off);
        }
        float mu = s * (1.f / D_DIM);
        float var = q * (1.f / D_DIM) - mu * mu;
        float rs = rsqrtf(var + LN_EPS);
        float o16[16];
#pragma unroll
        for (int j = 0; j < 16; ++j) o16[j] = (h[j] - mu) * rs * g[j] + be[j];
#pragma unroll
        for (int j = 0; j < 16; j += 4) *(float4*)&outp[row + j] = *(float4*)&o16[j];
    }
}

extern "C" void kernel_launch(void* const* d_in, const int* in_sizes, int n_in,
                              void* d_out, int out_size, void* d_ws, size_t ws_size,
                              hipStream_t stream) {
    const float* x       = (const float*)d_in[0];
    const float* W_in    = (const float*)d_in[1];
    const float* W_state = (const float*)d_in[2];
    const float* gamma   = (const float*)d_in[3];
    const float* beta    = (const float*)d_in[4];
    float* out = (float*)d_out;

    char* w = (char*)d_ws;
    size_t off = 0;
    auto carve = [&](size_t bytes) {
        void* p = w + off;
        off += (bytes + 255) & ~(size_t)255;
        return p;
    };
    _Float16* xh   = (_Float16*)carve((size_t)M_TOT * K_DIM * 2);           // 64 MiB
    _Float16* Wall = (_Float16*)carve((size_t)2 * D_DIM * K_DIM * 2);       // 4 MiB (W_g ; W_comb)
    _Float16* uarr = (_Float16*)carve((size_t)M_TOT * D_DIM * 2);           // 64 MiB
    _Float16* cand = (_Float16*)carve((size_t)M_TOT * D_DIM * 2);           // 64 MiB
    char* scratch  = (char*)carve((size_t)16 * 1024 * 1024);                // 16 MiB shared region
    _Float16* wvxT = (_Float16*)scratch;                                    // 2 MiB (early)
    _Float16* wst  = (_Float16*)(scratch + 2 * 1024 * 1024);                // 2 MiB (early)
    float* Ac = (float*)scratch;                                            // 8 MiB (late, also h0)
    float* Bc = (float*)(scratch + 8 * 1024 * 1024);                        // 8 MiB (late)
    float* wpart = (float*)cand;   // 16 MiB fp32 partials; cand dead until main GEMM

    // 1. merged prep (x cvt | gate cvt | W_state cvt | W_vx transpose)
    prep_all<<<4096, 256, 0, stream>>>(x, W_in, W_state, xh, Wall, wvxT, wst);

    // 2. W_comb = W_state @ W_vx -> Wall rows 1024..2047  (split-K x4)
    wcomb_splitk<<<256, 256, 0, stream>>>(wst, wvxT, wpart);
    wcomb_combine<<<1024, 256, 0, stream>>>(wpart, Wall + (size_t)D_DIM * K_DIM);

    // 3. fused projection + sigmoid + scan_pass1: [u|cand] tiles paired per block,
    //    epilogue composes per-16-row affine segments -> Ac/Bc
    gemm256<<<2048, 256, 0, stream>>>(xh, Wall, uarr, cand, Ac, Bc);

    // 4. cross-chunk scan + fused pass3/LN
    scan_pass2<<<(B_DIM * D_DIM) / 256, 256, 0, stream>>>(Ac, Bc);
    scan_ln<<<B_DIM * NCH, 64, 0, stream>>>(uarr, cand, Ac, gamma, beta, out);
}